// Round 10
// baseline (54.963 us; speedup 1.0000x reference)
//
#include <hip/hip_runtime.h>

typedef __attribute__((ext_vector_type(8))) short short8;
typedef __attribute__((ext_vector_type(4))) float float4v;
typedef __attribute__((address_space(1))) const unsigned int gu32;
typedef __attribute__((address_space(3))) unsigned int lu32;

#define TPB 256
#define NXPSI (4*4*8*16384)      /* 2097152 fp32 elements */
#define NGR   (NXPSI/4)          /* 524288 float4 granules */
#define ZPG   64                 /* zero-page ushort4 granules -> 512B */
#define PBYTE (NXPSI*2 + ZPG*8)  /* partial region byte offset = 4194816 */
#define NPART 3207168            /* partial floats: 8 kc-slices */
#define NOUT  739840             /* 640*4*289 */
#define NENT  21

// per-partial-tile base (floats), 19 16-col tiles. size(t) = 8*4*DYN*MV*16
__device__ __constant__ int TBASE[19] = {
    0, 278528, 557056, 835584, 1114112, 1392640, 1671168, 1949696, 2228224,
    2506752, 2617344, 2727936, 2838528, 2949120,
    3059712, 3100672, 3141632,
    3182592, 3194880};
__device__ __constant__ unsigned char J1T[10] = {0,0,0,0,1,1,1,2,2,3};
__device__ __constant__ unsigned char J2T[10] = {0,1,2,3,1,2,3,2,3,3};
__device__ __constant__ unsigned char TSTART[4] = {17,14,9,0};

// 21 block-entries, heavy-first. J2>=2: 32-wide (2 frags); J2<=1: 16-wide.
__device__ __constant__ unsigned char E_N0[NENT] = {
    0,32,64,96,128, 0,32,64,96,128, 0,32,64, 0,32,64, 0,16,32, 0,16};
__device__ __constant__ unsigned char E_MOFF[NENT] = {
    0,0,0,0,0, 16,16,16,16,16, 0,0,0, 16,16,16, 0,0,0, 0,0};
__device__ __constant__ unsigned char E_TG[NENT] = {
    0,2,4,6,8, 0,2,4,6,8, 9,11,13, 9,11,13, 14,15,16, 17,18};

static __device__ __forceinline__ unsigned short f2bf(float f) {
    unsigned int u = __builtin_bit_cast(unsigned int, f);
    u = (u + 0x7FFFu + ((u >> 16) & 1u)) >> 16;     // RNE, data has no NaN
    return (unsigned short)u;
}

__global__ __launch_bounds__(256)
void conv_bf16(const float* __restrict__ in, unsigned short* __restrict__ outw) {
    const int g = blockIdx.x * 256 + threadIdx.x;
    if (g < NGR) {
        const float4 v = reinterpret_cast<const float4*>(in)[g];
        reinterpret_cast<ushort4*>(outw)[g] =
            ushort4{f2bf(v.x), f2bf(v.y), f2bf(v.z), f2bf(v.w)};
    } else if (g < NGR + ZPG) {
        reinterpret_cast<ushort4*>(outw)[g] = ushort4{0, 0, 0, 0};
    }
}

// corr[p,b,dx,dy] = sum_{u,v} a[u,v]*b[(u-dx)%128,(v-dy)%128]; |dx|,|dy|<=r=2^j2.
// J2>=2: 32 output cols/block (2 B-frags share one A-frag). Waves split K.
template<int J2, bool PRE, bool PART>
static __device__ __forceinline__ void corr_body(
        const float* __restrict__ xpsi, const unsigned short* __restrict__ xbf,
        float* __restrict__ out, float* __restrict__ part,
        unsigned char* smem, int tgl, int n0, int moff, int b, int kc)
{
    constexpr int R    = 1 << J2;
    constexpr int DXN  = 2 * R + 1;
    constexpr int DYN  = DXN;
    constexpr int MV   = 8 * (J2 + 1);
    constexpr int ROWS = 16 + 2 * R;
    constexpr int ABUF = 16 * 256;                 // A buffer elements (16r x 2K x 128)
    constexpr int S    = DYN * MV * 16;            // floats per partial slice
    constexpr int W    = (J2 >= 2) ? 32 : 16;
    constexpr int F    = W / 16;

    unsigned short* a_lds = (unsigned short*)smem;               // 2 x 8KB
    unsigned short* b_lds = (unsigned short*)(smem + 4 * ABUF);

    const int k0    = kc * 16;
    const int vrows = (MV - moff < 16) ? MV - moff : 16;

    const int ch2lo = n0 / DXN;
    int nhi = n0 + W - 1; if (nhi > 8 * DXN - 1) nhi = 8 * DXN - 1;
    const int nimg = nhi / DXN - ch2lo + 1;

    const int tid  = threadIdx.x;
    const int lane = tid & 63;
    const int wv   = tid >> 6;
    const int c    = lane & 15;
    const int g    = lane >> 4;

    // frag A lane geometry
    const int ncolA  = n0 + c;
    const bool validA = ncolA < 8 * DXN;
    const int nccA   = validA ? ncolA : (8 * DXN - 1);
    const int ch2A   = nccA / DXN;
    const int dxiA   = nccA - ch2A * DXN;
    const int bstA   = ((ch2A - ch2lo) * ROWS + (2 * R - dxiA)) * 152;
    // frag B lane geometry
    const int ncolB  = n0 + 16 + c;
    const bool validB = (W == 32) && (ncolB < 8 * DXN);
    const int nccB   = (ncolB < 8 * DXN) ? ncolB : (8 * DXN - 1);
    const int ch2B   = nccB / DXN;
    const int dxiB   = nccB - ch2B * DXN;
    const int bstB   = ((ch2B - ch2lo) * ROWS + (2 * R - dxiB)) * 152;

    // ---- A stage: 16 rows x [2 K-rows x 128px], 16B-granule swizzle lo=(o&31)^ms
    float4 ar[4];
    auto stageA = [&](int sub, int bufi) {
        unsigned short* ab = a_lds + bufi * ABUF;
        #pragma unroll
        for (int it = 0; it < 2; ++it) {
            const int o  = it * TPB + tid;
            const int ms = o >> 5;
            const int lo = (o & 31) ^ ms;
            const int me = moff + ms;
            const int j1 = me >> 3, ch1 = me & 7;
            if (PRE) {
                const unsigned short* src = (ms < vrows)
                    ? xbf + ((((size_t)j1*4 + b)*8) + ch1) * 16384
                          + (k0 + sub * 2 + (lo >> 4)) * 128 + ((lo & 15) << 3)
                    : xbf + NXPSI + ((lo & 31) << 3);          // zero page
                __builtin_amdgcn_global_load_lds((gu32*)src, (lu32*)(ab + o * 8), 16, 0, 0);
            }
        }
    };
    auto loadA = [&](int sub) {                                // !PRE reg-staged
        #pragma unroll
        for (int it = 0; it < 2; ++it) {
            const int o  = it * TPB + tid;
            const int ms = o >> 5;
            const int lo = (o & 31) ^ ms;
            const int me = moff + ms;
            const int j1 = me >> 3, ch1 = me & 7;
            if (ms < vrows) {
                const float* s = xpsi + ((((size_t)j1*4 + b)*8) + ch1) * 16384
                               + (k0 + sub * 2 + (lo >> 4)) * 128 + ((lo & 15) << 3);
                ar[2*it]   = ((const float4*)s)[0];
                ar[2*it+1] = ((const float4*)s)[1];
            } else {
                ar[2*it] = float4{0,0,0,0}; ar[2*it+1] = float4{0,0,0,0};
            }
        }
    };
    auto writeA = [&](int bufi) {
        unsigned short* ab = a_lds + bufi * ABUF;
        #pragma unroll
        for (int it = 0; it < 2; ++it) {
            const int o = it * TPB + tid;
            const float4 f0 = ar[2*it], f1 = ar[2*it+1];
            *(ushort4*)(ab + o*8)   = ushort4{f2bf(f0.x),f2bf(f0.y),f2bf(f0.z),f2bf(f0.w)};
            *(ushort4*)(ab + o*8+4) = ushort4{f2bf(f1.x),f2bf(f1.y),f2bf(f1.z),f2bf(f1.w)};
        }
    };

    if (PRE) stageA(0, 0); else loadA(0);

    // ---- stage B once: [nimg][ROWS][144 +8pad], col tc <-> src (tc+R-16)&127 ----
    if (PRE && J2 >= 2) {
        for (int ci = 0; ci < nimg; ++ci) {
            const unsigned short* img = xbf + ((((size_t)J2*4 + b)*8) + ch2lo + ci) * 16384;
            const int ng2 = ROWS * 36;
            for (int i = tid; i < ng2; i += TPB) {
                const int tr = i / 36, tc = (i - tr * 36) * 4;
                const int sr = (k0 - R + tr) & 127;
                const int sc = (tc + R - 16) & 127;
                *(ushort4*)(b_lds + (ci * ROWS + tr) * 152 + tc) =
                    *(const ushort4*)(img + sr * 128 + sc);
            }
        }
    } else {
        const int tot = nimg * ROWS * 144;
        for (int i = tid; i < tot; i += TPB) {
            const int ci = i / (ROWS * 144);
            const int rr = i - ci * (ROWS * 144);
            const int tr = rr / 144, tc = rr - tr * 144;
            const int sr = (k0 - R + tr) & 127;
            const int sc = (tc + R - 16) & 127;
            const size_t off = ((((size_t)J2*4 + b)*8) + ch2lo + ci) * 16384 + sr * 128 + sc;
            b_lds[(ci * ROWS + tr) * 152 + tc] = PRE ? xbf[off] : f2bf(xpsi[off]);
        }
    }

    if (!PRE) writeA(0);

    float4v accA[DYN], accB[(W == 32) ? DYN : 1];
    #pragma unroll
    for (int i = 0; i < DYN; ++i) accA[i] = (float4v)0.f;
    if (W == 32) {
        #pragma unroll
        for (int i = 0; i < DYN; ++i) accB[i] = (float4v)0.f;
    }

    auto compute = [&](int sub, int bufi) {
        const char* abase = (const char*)(a_lds + bufi * ABUF);
        #pragma unroll
        for (int i2 = 0; i2 < 2; ++i2) {          // K-slice = wv + 4*i2
            const int loff = (((i2 << 8) | (wv << 6) | (g << 4))) ^ (c << 4);
            const short8 af0 = *(const short8*)(abase + c * 512 + loff);
            {   // frag A
                const unsigned short* bp = b_lds + bstA + (sub*2 + i2)*152 + (wv<<5) + (g<<3);
                const uint4 wA = *(const uint4*)bp;
                const uint4 wB = *(const uint4*)(bp + 8);
                const uint4 wC = *(const uint4*)(bp + 16);
                const unsigned int wd[12] = {wA.x,wA.y,wA.z,wA.w, wB.x,wB.y,wB.z,wB.w,
                                             wC.x,wC.y,wC.z,wC.w};
                #pragma unroll
                for (int dyi = 0; dyi < DYN; ++dyi) {
                    unsigned int o0,o1,o2,o3;
                    if ((dyi & 1) == 0) {
                        const int bb = 8 - (dyi >> 1);
                        o0=wd[bb]; o1=wd[bb+1]; o2=wd[bb+2]; o3=wd[bb+3];
                    } else {
                        const int bb = (15 - dyi) >> 1;
                        o0=(wd[bb]>>16)|(wd[bb+1]<<16);   o1=(wd[bb+1]>>16)|(wd[bb+2]<<16);
                        o2=(wd[bb+2]>>16)|(wd[bb+3]<<16); o3=(wd[bb+3]>>16)|(wd[bb+4]<<16);
                    }
                    union { unsigned int u[4]; short8 s; } bq;
                    bq.u[0]=o0; bq.u[1]=o1; bq.u[2]=o2; bq.u[3]=o3;
                    accA[dyi] = __builtin_amdgcn_mfma_f32_16x16x32_bf16(
                        af0, bq.s, accA[dyi], 0, 0, 0);
                }
            }
            if (W == 32) {   // frag B shares af0
                const unsigned short* bp = b_lds + bstB + (sub*2 + i2)*152 + (wv<<5) + (g<<3);
                const uint4 wA = *(const uint4*)bp;
                const uint4 wB = *(const uint4*)(bp + 8);
                const uint4 wC = *(const uint4*)(bp + 16);
                const unsigned int wd[12] = {wA.x,wA.y,wA.z,wA.w, wB.x,wB.y,wB.z,wB.w,
                                             wC.x,wC.y,wC.z,wC.w};
                #pragma unroll
                for (int dyi = 0; dyi < DYN; ++dyi) {
                    unsigned int o0,o1,o2,o3;
                    if ((dyi & 1) == 0) {
                        const int bb = 8 - (dyi >> 1);
                        o0=wd[bb]; o1=wd[bb+1]; o2=wd[bb+2]; o3=wd[bb+3];
                    } else {
                        const int bb = (15 - dyi) >> 1;
                        o0=(wd[bb]>>16)|(wd[bb+1]<<16);   o1=(wd[bb+1]>>16)|(wd[bb+2]<<16);
                        o2=(wd[bb+2]>>16)|(wd[bb+3]<<16); o3=(wd[bb+3]>>16)|(wd[bb+4]<<16);
                    }
                    union { unsigned int u[4]; short8 s; } bq;
                    bq.u[0]=o0; bq.u[1]=o1; bq.u[2]=o2; bq.u[3]=o3;
                    accB[dyi] = __builtin_amdgcn_mfma_f32_16x16x32_bf16(
                        af0, bq.s, accB[dyi], 0, 0, 0);
                }
            }
        }
    };

    __syncthreads();
    for (int sub = 0; sub < 8; ++sub) {
        if (sub < 7) { if (PRE) stageA(sub + 1, (sub + 1) & 1); else loadA(sub + 1); }
        compute(sub, sub & 1);
        if (!PRE && sub < 7) writeA((sub + 1) & 1);
        __syncthreads();
    }

    if (PART) {
        // in-block cross-wave reduction via LDS (reuse smem), plain coalesced stores
        auto reduce_store = [&](auto& accv, int tg, int nb) {
            constexpr int NG  = (DYN < 9) ? DYN : 9;
            constexpr int NPH = (DYN + NG - 1) / NG;
            float* red = (float*)smem;
            float* pt  = part + TBASE[tg] + (size_t)(kc * 4 + b) * S;
            #pragma unroll
            for (int ph = 0; ph < NPH; ++ph) {
                const int d0 = ph * NG;
                const int nd = (DYN - d0 < NG) ? (DYN - d0) : NG;
                __syncthreads();
                #pragma unroll
                for (int dl = 0; dl < NG; ++dl) {
                    if (dl >= nd) break;
                    *(float4v*)(red + ((wv * NG + dl) * 64 + lane) * 4) = accv[d0 + dl];
                }
                __syncthreads();
                for (int i = tid; i < nd * 64; i += TPB) {
                    const int dl = i >> 6, ln = i & 63;
                    const float4v s0 = *(const float4v*)(red + ((0*NG + dl)*64 + ln)*4);
                    const float4v s1 = *(const float4v*)(red + ((1*NG + dl)*64 + ln)*4);
                    const float4v s2 = *(const float4v*)(red + ((2*NG + dl)*64 + ln)*4);
                    const float4v s3 = *(const float4v*)(red + ((3*NG + dl)*64 + ln)*4);
                    const float4v s = (s0 + s1) + (s2 + s3);
                    const int cc = ln & 15, gg = ln >> 4;
                    if (nb + cc < 8 * DXN) {
                        const int dyi = d0 + dl;
                        #pragma unroll
                        for (int t2 = 0; t2 < 4; ++t2) {
                            const int ml = (gg << 2) + t2;
                            if (ml < vrows)
                                pt[(dyi * MV + moff + ml) * 16 + cc] = s[t2];
                        }
                    }
                }
            }
        };
        reduce_store(accA, tgl, n0);
        if (W == 32 && n0 + 16 < 8 * DXN)          // block-uniform guard
            reduce_store(accB, tgl + 1, n0 + 16);
        return;
    }

    // fallback: device atomics
    #pragma unroll
    for (int f = 0; f < F; ++f) {
        const bool vf = f ? validB : validA;
        if (!vf) continue;
        const int ch2 = f ? ch2B : ch2A;
        const int dx  = (f ? dxiB : dxiA) - R;
        const int xo  = dx < 0 ? dx + 17 : dx;
        #pragma unroll
        for (int dyi = 0; dyi < DYN; ++dyi) {
            const int dy = dyi - R;
            const int yo = dy < 0 ? dy + 17 : dy;
            #pragma unroll
            for (int t2 = 0; t2 < 4; ++t2) {
                const int ml = (g << 2) + t2;
                if (ml >= vrows) continue;
                const int m = moff + ml;
                const int j1 = m >> 3, ch1 = m & 7;
                const int pb = ((j1 * (9 - j1)) >> 1) + (J2 - j1);
                const int p  = pb * 64 + ((ch1 >> 1) << 4) + ((ch2 >> 1) << 2)
                             + ((ch1 & 1) << 1) + (ch2 & 1);
                const float val = f ? accB[dyi][t2] : accA[dyi][t2];
                atomicAdd(out + (size_t)(p * 4 + b) * 289 + xo * 17 + yo, val);
            }
        }
    }
}

// bid -> entry-major (heavy first), (b,kc) inner.
template<bool PRE, bool PART>
__global__ __launch_bounds__(TPB, 2)
void corr_v10(const float* __restrict__ xpsi, const unsigned short* __restrict__ xbf,
              float* __restrict__ out, float* __restrict__ part)
{
    __shared__ __align__(16) unsigned char smem[52864];
    const int bid = blockIdx.x;
    const int e   = bid >> 5;
    const int rem = bid & 31;
    const int b   = rem & 3;
    const int kc  = rem >> 2;
    const int n0   = E_N0[e];
    const int moff = E_MOFF[e];
    const int tgl  = E_TG[e];
    if (e < 10)      corr_body<3, PRE, PART>(xpsi, xbf, out, part, smem, tgl, n0, moff, b, kc);
    else if (e < 16) corr_body<2, PRE, PART>(xpsi, xbf, out, part, smem, tgl, n0, moff, b, kc);
    else if (e < 19) corr_body<1, PRE, PART>(xpsi, xbf, out, part, smem, tgl, n0, moff, b, kc);
    else             corr_body<0, PRE, PART>(xpsi, xbf, out, part, smem, tgl, n0, moff, b, kc);
}

// Full-range reduce: sums 8 kc slices inside the mask, writes zeros outside.
__global__ __launch_bounds__(256)
void reduce_k(const float* __restrict__ part, float* __restrict__ out)
{
    const int o = blockIdx.x * 256 + threadIdx.x;
    if (o >= NOUT) return;
    const int p  = o / 1156;
    const int r1 = o - p * 1156;
    const int b  = r1 / 289;
    const int s  = r1 - b * 289;
    const int xo = s / 17, yo = s - xo * 17;
    const int pb = p >> 6, cc = p & 63;
    const int j1 = J1T[pb], j2 = J2T[pb];
    const int R  = 1 << j2;
    const int dx = xo <= 8 ? xo : xo - 17;
    const int dy = yo <= 8 ? yo : yo - 17;
    float v = 0.f;
    if (dx >= -R && dx <= R && dy >= -R && dy <= R) {
        const int ch1 = ((cc >> 4) & 3) * 2 + ((cc >> 1) & 1);
        const int ch2 = ((cc >> 2) & 3) * 2 + (cc & 1);
        const int DYN = 2 * R + 1, MV = 8 * (j2 + 1);
        const int ncol = ch2 * DYN + (dx + R);
        const int t = TSTART[j2] + (ncol >> 4);
        const int c = ncol & 15;
        const int m = j1 * 8 + ch1;
        const int S = DYN * MV * 16;
        const float* q = part + TBASE[t]
                       + ((size_t)(b * DYN + (dy + R)) * MV + m) * 16 + c;
        #pragma unroll
        for (int kc = 0; kc < 8; ++kc) v += q[(size_t)kc * 4 * S];
    }
    out[o] = v;
}

extern "C" void kernel_launch(void* const* d_in, const int* in_sizes, int n_in,
                              void* d_out, int out_size, void* d_ws, size_t ws_size,
                              hipStream_t stream) {
    const float* xpsi = (const float*)d_in[0];
    float* out = (float*)d_out;

    if (ws_size >= (size_t)PBYTE + (size_t)NPART * 4) {
        unsigned short* xbf = (unsigned short*)d_ws;
        float* part = (float*)((char*)d_ws + PBYTE);
        conv_bf16<<<(NGR + ZPG + 255) / 256, 256, 0, stream>>>(xpsi, xbf);
        corr_v10<true, true><<<NENT * 32, TPB, 0, stream>>>(xpsi, xbf, out, part);
        reduce_k<<<(NOUT + 255) / 256, 256, 0, stream>>>(part, out);
    } else if (ws_size >= (size_t)PBYTE) {
        unsigned short* xbf = (unsigned short*)d_ws;
        hipMemsetAsync(d_out, 0, (size_t)out_size * sizeof(float), stream);
        conv_bf16<<<(NGR + ZPG + 255) / 256, 256, 0, stream>>>(xpsi, xbf);
        corr_v10<true, false><<<NENT * 32, TPB, 0, stream>>>(xpsi, xbf, out, nullptr);
    } else {
        hipMemsetAsync(d_out, 0, (size_t)out_size * sizeof(float), stream);
        corr_v10<false, false><<<NENT * 32, TPB, 0, stream>>>(xpsi, nullptr, out, nullptr);
    }
}